// Round 2
// baseline (699.904 us; speedup 1.0000x reference)
//
#include <hip/hip_runtime.h>
#include <hip/hip_bf16.h>

#define HH 512
#define WW 512

// conv1, fused with foveated gather.
// Grid: (4 c1-groups, n_img). Block: 256.
// h1 layout: [img_local][64 c1][64][64] f32
__global__ __launch_bounds__(256) void conv1_kernel(
    const float* __restrict__ x, const float* __restrict__ l,
    const float* __restrict__ w1, const float* __restrict__ b1,
    float* __restrict__ h1, int bk0)
{
    const int img = blockIdx.y;
    const int bk  = bk0 + img;
    const int b   = bk / 3, k = bk % 3;
    const int c1g = blockIdx.x;            // 0..3, 16 c1 each
    const int step = 1 << k;
    const int half = 32 << k;              // size/2

    const float ly = l[b * 2 + 0], lx = l[b * 2 + 1];
    int cy = (int)floorf((0.5f * (ly + 1.0f)) * 512.0f);
    int cx = (int)floorf((0.5f * (lx + 1.0f)) * 512.0f);
    cy = min(max(cy, 0), 512);
    cx = min(max(cx, 0), 512);
    const int sy = cy - half, sx = cx - half;

    // phi image + 1-px zero border (conv1 SAME zero padding)
    __shared__ float in_s[3][66][66];      // 52272 B
    const int t = threadIdx.x;
    for (int i = t; i < 3 * 66 * 66; i += 256) {
        const int c  = i / (66 * 66);
        const int r  = i % (66 * 66);
        const int yy = r / 66, xx = r % 66;
        float v = 0.0f;
        if (yy >= 1 && yy <= 64 && xx >= 1 && xx <= 64) {
            const int iy = sy + (yy - 1) * step;   // nearest resize == stride-step sample
            const int ix = sx + (xx - 1) * step;
            if (iy >= 0 && iy < HH && ix >= 0 && ix < WW)
                v = x[(((size_t)b * 3 + c) * HH + iy) * WW + ix];
        }
        in_s[c][yy][xx] = v;
    }
    __syncthreads();

    const int xo = t & 63;
    const int y0 = t >> 6;                 // 0..3
    #pragma unroll 1
    for (int yi = 0; yi < 16; ++yi) {
        const int yo = (y0 << 4) + yi;
        float in_r[27];
        #pragma unroll
        for (int c = 0; c < 3; ++c)
            #pragma unroll
            for (int kh = 0; kh < 3; ++kh)
                #pragma unroll
                for (int kw = 0; kw < 3; ++kw)
                    in_r[c * 9 + kh * 3 + kw] = in_s[c][yo + kh][xo + kw];

        #pragma unroll
        for (int c1i = 0; c1i < 16; ++c1i) {
            const int c1 = c1g * 16 + c1i;
            const float* wp = w1 + c1 * 27;    // block-uniform -> s_load
            float acc = b1[c1];
            #pragma unroll
            for (int j = 0; j < 27; ++j) acc = fmaf(wp[j], in_r[j], acc);
            acc = fmaxf(acc, 0.0f);
            h1[(((size_t)img * 64 + c1) * 64 + yo) * 64 + xo] = acc;
        }
    }
}

// conv2: 3x3 stride 2, XLA SAME on 64 -> 32: pad_low=0, pad_high=1.
// Grid: (8 c2-groups, n_img). Block: 256. Thread owns 2x2 output block.
__global__ __launch_bounds__(256) void conv2_kernel(
    const float* __restrict__ h1, const float* __restrict__ w2,
    const float* __restrict__ b2, float* __restrict__ out, int bk0)
{
    const int img = blockIdx.y;
    const int bk  = bk0 + img;
    const int c2g = blockIdx.x;            // 0..7
    const int t   = threadIdx.x;
    const int by  = t >> 4, bx = t & 15;   // 16x16 thread grid of 2x2 out blocks
    const int r0  = by * 4, c0 = bx * 4;   // input base row/col (stride-2 conv)

    float acc[16][4];
    #pragma unroll
    for (int i = 0; i < 16; ++i) {
        const float bb = b2[c2g * 16 + i];
        acc[i][0] = bb; acc[i][1] = bb; acc[i][2] = bb; acc[i][3] = bb;
    }

    const float* hb = h1 + (size_t)img * 64 * 64 * 64;
    const bool interior = (by < 15) && (bx < 15);

    #pragma unroll 1
    for (int c1 = 0; c1 < 64; ++c1) {
        float in_r[5][5];
        const float* hp = hb + (size_t)c1 * 64 * 64;
        if (interior) {
            #pragma unroll
            for (int rr = 0; rr < 5; ++rr) {
                const float* rp = hp + (r0 + rr) * 64 + c0;   // 16B aligned
                const float4 v = *(const float4*)rp;
                in_r[rr][0] = v.x; in_r[rr][1] = v.y;
                in_r[rr][2] = v.z; in_r[rr][3] = v.w;
                in_r[rr][4] = rp[4];
            }
        } else {
            #pragma unroll
            for (int rr = 0; rr < 5; ++rr) {
                const int r = r0 + rr;
                #pragma unroll
                for (int cc = 0; cc < 5; ++cc) {
                    const int c = c0 + cc;
                    in_r[rr][cc] = (r < 64 && c < 64) ? hp[r * 64 + c] : 0.0f;
                }
            }
        }
        #pragma unroll
        for (int c2i = 0; c2i < 16; ++c2i) {
            const float* wp = w2 + ((size_t)(c2g * 16 + c2i) * 64 + c1) * 9; // uniform -> s_load
            #pragma unroll
            for (int kh = 0; kh < 3; ++kh)
                #pragma unroll
                for (int kw = 0; kw < 3; ++kw) {
                    const float w = wp[kh * 3 + kw];
                    acc[c2i][0] = fmaf(w, in_r[kh    ][kw    ], acc[c2i][0]);
                    acc[c2i][1] = fmaf(w, in_r[kh    ][kw + 2], acc[c2i][1]);
                    acc[c2i][2] = fmaf(w, in_r[kh + 2][kw    ], acc[c2i][2]);
                    acc[c2i][3] = fmaf(w, in_r[kh + 2][kw + 2], acc[c2i][3]);
                }
        }
    }

    // out layout: [bk][128][32][32]
    float* ob = out + ((size_t)bk * 128 + c2g * 16) * 32 * 32;
    #pragma unroll
    for (int c2i = 0; c2i < 16; ++c2i) {
        float2 v0 = { fmaxf(acc[c2i][0], 0.0f), fmaxf(acc[c2i][1], 0.0f) };
        float2 v1 = { fmaxf(acc[c2i][2], 0.0f), fmaxf(acc[c2i][3], 0.0f) };
        float* op = ob + (size_t)c2i * 1024 + (by * 2) * 32 + bx * 2;
        *(float2*)op        = v0;   // row y=2*by
        *(float2*)(op + 32) = v1;   // row y=2*by+1
    }
}

extern "C" void kernel_launch(void* const* d_in, const int* in_sizes, int n_in,
                              void* d_out, int out_size, void* d_ws, size_t ws_size,
                              hipStream_t stream) {
    const float* x  = (const float*)d_in[0];
    const float* l  = (const float*)d_in[1];
    const float* w1 = (const float*)d_in[2];
    const float* b1 = (const float*)d_in[3];
    const float* w2 = (const float*)d_in[4];
    const float* b2 = (const float*)d_in[5];
    float* out = (float*)d_out;
    float* h1  = (float*)d_ws;

    const int total_imgs = 64 * 3;                       // B*K = 192
    const size_t per_img = (size_t)64 * 64 * 64 * sizeof(float);  // 1 MB
    int ipc = (int)(ws_size / per_img);                  // images per chunk
    if (ipc > total_imgs) ipc = total_imgs;
    if (ipc < 1) ipc = 1;

    for (int bk0 = 0; bk0 < total_imgs; bk0 += ipc) {
        const int n = (total_imgs - bk0 < ipc) ? (total_imgs - bk0) : ipc;
        dim3 blk(256);
        dim3 g1(4, n);
        conv1_kernel<<<g1, blk, 0, stream>>>(x, l, w1, b1, h1, bk0);
        dim3 g2(8, n);
        conv2_kernel<<<g2, blk, 0, stream>>>(h1, w2, b2, out, bk0);
    }
}

// Round 4
// 158.850 us; speedup vs baseline: 4.4061x; 4.4061x over previous
//
#include <hip/hip_runtime.h>
#include <hip/hip_bf16.h>

typedef __attribute__((ext_vector_type(4))) float  f32x4;
typedef __attribute__((ext_vector_type(8))) _Float16 f16x8;

#define LDA1 40   // conv1 A_lds row stride in fp16 elems (80 B: 16B-aligned rows, ~2-way banks)

// ---- weight pre-transform: w1 -> Bt1[64 n][32 k] f16 (k=c*9+kh*3+kw, pad 27..31 = 0)
//                            w2 -> Bt2[9 tap][128 c2][64 c1] f16
__global__ void transform_kernel(const float* __restrict__ w1, const float* __restrict__ w2,
                                 _Float16* __restrict__ Bt1, _Float16* __restrict__ Bt2)
{
    const int i = blockIdx.x * 256 + threadIdx.x;
    if (i < 64 * 32) {
        const int n = i >> 5, k = i & 31;
        const float v = (k < 27) ? w1[n * 27 + k] : 0.0f;
        Bt1[i] = (_Float16)v;
    }
    const int j = i - 64 * 32;
    if (j >= 0 && j < 9 * 128 * 64) {
        const int tap = j / (128 * 64);
        const int rem = j % (128 * 64);
        const int n = rem >> 6;          // c2
        const int c1 = rem & 63;
        Bt2[j] = (_Float16)w2[((size_t)n * 64 + c1) * 9 + tap];
    }
}

// ---- conv1 (gather + 3x3 s1 SAME + ReLU) as MFMA: M=4096 px/img, N=64, K=27->32
// h1 channels-last: [img][pixel m=y*64+x][c1] f16
__global__ __launch_bounds__(256) void conv1_mfma(
    const float* __restrict__ x, const float* __restrict__ l,
    const _Float16* __restrict__ Bt1, const float* __restrict__ b1,
    _Float16* __restrict__ h1, int bk0)
{
    const int img = blockIdx.y;
    const int bk  = bk0 + img;
    const int b   = bk / 3, ksc = bk % 3;
    const int step = 1 << ksc;
    const int half = 32 << ksc;
    const int mbase = blockIdx.x * 256;       // 16 chunks of 256 pixels

    const float ly = l[b * 2 + 0], lx = l[b * 2 + 1];
    int cy = (int)floorf(0.5f * (ly + 1.0f) * 512.0f);
    int cx = (int)floorf(0.5f * (lx + 1.0f) * 512.0f);
    cy = min(max(cy, 0), 512);
    cx = min(max(cx, 0), 512);
    const int sy = cy - half, sx = cx - half;

    __shared__ _Float16 A_lds[256 * LDA1];    // 20 KB

    const int t = threadIdx.x;
    {   // im2col build: thread t owns pixel m = mbase+t, k = 0..31
        const int m  = mbase + t;
        const int py = m >> 6, px = m & 63;
        const float* xb = x + (size_t)b * 3 * 512 * 512;
        _Float16* arow = &A_lds[t * LDA1];
        #pragma unroll
        for (int k = 0; k < 27; ++k) {
            const int c = k / 9, r = k % 9, kh = r / 3, kw = r % 3;  // compile-time
            const int yy = py + kh - 1, xx = px + kw - 1;            // SAME pad 1
            const int iy = sy + yy * step, ix = sx + xx * step;      // nearest == stride sample
            float v = 0.0f;
            if (yy >= 0 && yy < 64 && xx >= 0 && xx < 64 &&
                iy >= 0 && iy < 512 && ix >= 0 && ix < 512)
                v = xb[(size_t)c * 512 * 512 + iy * 512 + ix];
            arow[k] = (_Float16)v;
        }
        #pragma unroll
        for (int k = 27; k < 32; ++k) arow[k] = (_Float16)0.0f;
    }
    __syncthreads();

    const int wave = t >> 6, lane = t & 63;
    const int lrow = lane & 15, kb = lane >> 4;

    f16x8 bfr[4];
    #pragma unroll
    for (int nf = 0; nf < 4; ++nf)
        bfr[nf] = *(const f16x8*)(Bt1 + ((size_t)(nf * 16 + lrow)) * 32 + kb * 8);

    f32x4 acc[4][4];
    #pragma unroll
    for (int mf = 0; mf < 4; ++mf)
        #pragma unroll
        for (int nf = 0; nf < 4; ++nf)
            #pragma unroll
            for (int r = 0; r < 4; ++r) acc[mf][nf][r] = 0.0f;

    #pragma unroll
    for (int mf = 0; mf < 4; ++mf) {
        const int mrow = wave * 4 + mf;       // m-frag 0..15
        const f16x8 afr = *(const f16x8*)(&A_lds[(mrow * 16 + lrow) * LDA1 + kb * 8]);
        #pragma unroll
        for (int nf = 0; nf < 4; ++nf)
            acc[mf][nf] = __builtin_amdgcn_mfma_f32_16x16x32_f16(afr, bfr[nf], acc[mf][nf], 0, 0, 0);
    }

    _Float16* hb = h1 + (size_t)img * 4096 * 64;
    #pragma unroll
    for (int mf = 0; mf < 4; ++mf) {
        const int m0 = mbase + (wave * 4 + mf) * 16 + kb * 4;   // C/D: row=(lane>>4)*4+r
        #pragma unroll
        for (int nf = 0; nf < 4; ++nf) {
            const int c1 = nf * 16 + lrow;                       // C/D: col=lane&15
            const float bb = b1[c1];
            #pragma unroll
            for (int r = 0; r < 4; ++r) {
                const float v = fmaxf(acc[mf][nf][r] + bb, 0.0f);
                hb[(size_t)(m0 + r) * 64 + c1] = (_Float16)v;
            }
        }
    }
}

// ---- conv2 (3x3 s2, XLA SAME pad(0,1), + ReLU) as MFMA:
// per image GEMM M=1024 px(32x32), N=128 c2, K=576 (tap-major: k = tap*64 + c1)
__global__ __launch_bounds__(256) void conv2_mfma(
    const _Float16* __restrict__ h1, const _Float16* __restrict__ Bt2,
    const float* __restrict__ b2, float* __restrict__ out, int bk0)
{
    const int img = blockIdx.y;
    const int bk  = bk0 + img;
    const int mchunk = blockIdx.x;            // 0..3 -> 256 pixels
    const int t = threadIdx.x, wave = t >> 6, lane = t & 63;
    const int lrow = lane & 15, kb = lane >> 4;

    f32x4 acc[4][8];
    #pragma unroll
    for (int mf = 0; mf < 4; ++mf)
        #pragma unroll
        for (int nf = 0; nf < 8; ++nf)
            #pragma unroll
            for (int r = 0; r < 4; ++r) acc[mf][nf][r] = 0.0f;

    const _Float16* hb = h1 + (size_t)img * 4096 * 64;

    #pragma unroll 1
    for (int tap = 0; tap < 9; ++tap) {
        const int kh = (tap >= 6) ? 2 : ((tap >= 3) ? 1 : 0);
        const int kw = tap - kh * 3;
        #pragma unroll
        for (int c1h = 0; c1h < 2; ++c1h) {
            f16x8 bfr[8];
            #pragma unroll
            for (int nf = 0; nf < 8; ++nf)
                bfr[nf] = *(const f16x8*)(Bt2 + ((size_t)tap * 128 + nf * 16 + lrow) * 64
                                              + c1h * 32 + kb * 8);
            #pragma unroll
            for (int mf = 0; mf < 4; ++mf) {
                const int m  = mchunk * 256 + (wave * 4 + mf) * 16 + lrow;  // A row = lane&15
                const int oy = m >> 5, ox = m & 31;
                const int y  = 2 * oy + kh, x2 = 2 * ox + kw;               // pad_low=0
                f16x8 afr;
                #pragma unroll
                for (int j = 0; j < 8; ++j) afr[j] = (_Float16)0.0f;
                if (y < 64 && x2 < 64)
                    afr = *(const f16x8*)(hb + ((size_t)y * 64 + x2) * 64 + c1h * 32 + kb * 8);
                #pragma unroll
                for (int nf = 0; nf < 8; ++nf)
                    acc[mf][nf] = __builtin_amdgcn_mfma_f32_16x16x32_f16(afr, bfr[nf], acc[mf][nf], 0, 0, 0);
            }
        }
    }

    float* ob = out + (size_t)bk * 128 * 1024;
    #pragma unroll
    for (int mf = 0; mf < 4; ++mf) {
        const int m0 = mchunk * 256 + (wave * 4 + mf) * 16 + kb * 4;
        #pragma unroll
        for (int nf = 0; nf < 8; ++nf) {
            const int c2 = nf * 16 + lrow;
            const float bb = b2[c2];
            f32x4 v;
            #pragma unroll
            for (int r = 0; r < 4; ++r) v[r] = fmaxf(acc[mf][nf][r] + bb, 0.0f);
            *(f32x4*)(ob + (size_t)c2 * 1024 + m0) = v;   // 4 consecutive px, 16B aligned
        }
    }
}

extern "C" void kernel_launch(void* const* d_in, const int* in_sizes, int n_in,
                              void* d_out, int out_size, void* d_ws, size_t ws_size,
                              hipStream_t stream) {
    const float* x  = (const float*)d_in[0];
    const float* l  = (const float*)d_in[1];
    const float* w1 = (const float*)d_in[2];
    const float* b1 = (const float*)d_in[3];
    const float* w2 = (const float*)d_in[4];
    const float* b2 = (const float*)d_in[5];
    float* out = (float*)d_out;

    _Float16* Bt1 = (_Float16*)d_ws;                                   // 2048  f16
    _Float16* Bt2 = Bt1 + 64 * 32;                                     // 73728 f16
    _Float16* h1  = (_Float16*)((char*)d_ws + 160 * 1024);             // chunked

    const int total_imgs = 192;                                        // B*K
    const size_t per_img = (size_t)4096 * 64 * sizeof(_Float16);       // 512 KB
    size_t h1_cap = (ws_size > 160 * 1024) ? ws_size - 160 * 1024 : 0;
    int ipc = (int)(h1_cap / per_img);
    if (ipc > total_imgs) ipc = total_imgs;
    if (ipc < 1) ipc = 1;

    transform_kernel<<<296, 256, 0, stream>>>(w1, w2, Bt1, Bt2);

    for (int bk0 = 0; bk0 < total_imgs; bk0 += ipc) {
        const int n = (total_imgs - bk0 < ipc) ? (total_imgs - bk0) : ipc;
        conv1_mfma<<<dim3(16, n), 256, 0, stream>>>(x, l, Bt1, b1, h1, bk0);
        conv2_mfma<<<dim3(4, n), 256, 0, stream>>>(h1, Bt2, b2, out, bk0);
    }
}